// Round 2
// baseline (737.817 us; speedup 1.0000x reference)
//
#include <hip/hip_runtime.h>

typedef short short8 __attribute__((ext_vector_type(8)));
typedef float f32x4 __attribute__((ext_vector_type(4)));

#define S_   64
#define NL_  5000
#define PD_  1024
#define LD_  768
#define DIM_ 512
#define OD_  512

__device__ __forceinline__ ushort f2bf(float f) {
    union { float f; unsigned u; } v; v.f = f;
    unsigned r = v.u + 0x7fffu + ((v.u >> 16) & 1u);   // RNE
    return (ushort)(r >> 16);
}

// ---- W2 f32->bf16 ----------------------------------------------------------
__global__ void k_cvt_w2(const float* __restrict__ W2, ushort* __restrict__ out) {
    int idx = blockIdx.x * 256 + threadIdx.x;      // 4 elems each
    float4 v = *(const float4*)(W2 + idx * 4);
    ushort4 o;
    o.x = f2bf(v.x); o.y = f2bf(v.y); o.z = f2bf(v.z); o.w = f2bf(v.w);
    *(ushort4*)(out + idx * 4) = o;
}

// ---- M_lT[o][ld] = sum_dim W_l[dim][ld] * W1[o][512+dim]  (bf16 out) -------
__global__ void k_mlt(const float* __restrict__ W_l, const float* __restrict__ W1,
                      ushort* __restrict__ MlT) {
    __shared__ float w1r[8][DIM_];
    int o0 = blockIdx.y * 8;
    int ld = blockIdx.x * 256 + threadIdx.x;
    for (int i = threadIdx.x; i < 8 * DIM_; i += 256)
        w1r[i >> 9][i & 511] = W1[(o0 + (i >> 9)) * (2 * DIM_) + DIM_ + (i & 511)];
    __syncthreads();
    float acc[8] = {};
    for (int dim = 0; dim < DIM_; dim++) {
        float wl = W_l[dim * LD_ + ld];
#pragma unroll
        for (int oi = 0; oi < 8; oi++) acc[oi] += w1r[oi][dim] * wl;
    }
#pragma unroll
    for (int oi = 0; oi < 8; oi++) MlT[(o0 + oi) * LD_ + ld] = f2bf(acc[oi]);
}

// ---- generic tiny f32 GEMM: C[s][o] = sum_k A[s][k] * W[o*ldw + k] ---------
__global__ void k_dot(const float* __restrict__ A, int lda, int K,
                      const float* __restrict__ W, int ldw,
                      float* __restrict__ C) {
    __shared__ float arow[1024];
    int s = blockIdx.x, o = threadIdx.x;
    for (int k = threadIdx.x; k < K; k += 512) arow[k] = A[s * lda + k];
    __syncthreads();
    const float* wr = W + o * ldw;
    float acc = 0.f;
    for (int k = 0; k < K; k++) acc += arow[k] * wr[k];
    C[s * DIM_ + o] = acc;
}

// ---- hl[5000][512] = bf16(emb[L]) @ MlT, MFMA, gather+convert fused --------
__global__ __launch_bounds__(512) void k_hl(const float* __restrict__ emb,
                                            const int* __restrict__ L,
                                            const ushort* __restrict__ MlT,
                                            float* __restrict__ hl) {
    int t = threadIdx.x;
    int w = t >> 6, l = t & 63, lg = l >> 4, ll = l & 15;
    int r0 = blockIdx.x * 64;
    const float* arow[4];
#pragma unroll
    for (int mt = 0; mt < 4; mt++) {
        int r = r0 + mt * 16 + ll;
        if (r >= NL_) r = NL_ - 1;
        arow[mt] = emb + (long long)L[r] * LD_ + 8 * lg;
    }
    f32x4 acc[4][4] = {};
    for (int k = 0; k < LD_; k += 32) {
        short8 a[4], b[4];
#pragma unroll
        for (int mt = 0; mt < 4; mt++) {
            float4 v0 = *(const float4*)(arow[mt] + k);
            float4 v1 = *(const float4*)(arow[mt] + k + 4);
            union { ushort u[8]; short8 v; } pk;
            pk.u[0] = f2bf(v0.x); pk.u[1] = f2bf(v0.y);
            pk.u[2] = f2bf(v0.z); pk.u[3] = f2bf(v0.w);
            pk.u[4] = f2bf(v1.x); pk.u[5] = f2bf(v1.y);
            pk.u[6] = f2bf(v1.z); pk.u[7] = f2bf(v1.w);
            a[mt] = pk.v;
        }
#pragma unroll
        for (int ot = 0; ot < 4; ot++) {
            int o = w * 64 + ot * 16 + ll;
            b[ot] = *(const short8*)(MlT + o * LD_ + k + 8 * lg);
        }
#pragma unroll
        for (int mt = 0; mt < 4; mt++)
#pragma unroll
            for (int ot = 0; ot < 4; ot++)
                acc[mt][ot] = __builtin_amdgcn_mfma_f32_16x16x32_bf16(a[mt], b[ot], acc[mt][ot], 0, 0, 0);
    }
#pragma unroll
    for (int mt = 0; mt < 4; mt++)
#pragma unroll
        for (int ot = 0; ot < 4; ot++)
#pragma unroll
            for (int reg = 0; reg < 4; reg++) {
                int r = r0 + mt * 16 + lg * 4 + reg;   // C/D: col=lane&15, row=(lane>>4)*4+reg
                if (r < NL_) hl[(long long)r * DIM_ + w * 64 + ot * 16 + ll] = acc[mt][ot][reg];
            }
}

// ---- main fused kernel: 64 (s,n) rows per block ----------------------------
__global__ __launch_bounds__(512) void k_main(const float* __restrict__ hp,
                                              const float* __restrict__ hl,
                                              const float* __restrict__ b1,
                                              const ushort* __restrict__ W2b,
                                              const float* __restrict__ b2,
                                              const float* __restrict__ W3,
                                              const float* __restrict__ b3,
                                              float* __restrict__ out) {
    __shared__ ushort h1[64 * DIM_];   // 64 KiB, XOR-swizzled; front reused as logit acc
    int t = threadIdx.x;
    int r0 = blockIdx.x * 64;

    // ---- stage h1 = bf16(relu(hp[s] + hl[n] + b1)) ----
    {
        int row = t >> 3;                 // 64 rows, 8 threads each
        int dc  = (t & 7) * 64;           // 64 contiguous d per thread
        int r = r0 + row;
        int s = r / NL_, n = r - s * NL_;
        const float* hpr = hp + s * DIM_ + dc;
        const float* hlr = hl + (long long)n * DIM_ + dc;
        const float* b1r = b1 + dc;
#pragma unroll
        for (int j = 0; j < 64; j += 8) {
            float4 a0 = *(const float4*)(hpr + j);
            float4 a1 = *(const float4*)(hpr + j + 4);
            float4 c0 = *(const float4*)(hlr + j);
            float4 c1 = *(const float4*)(hlr + j + 4);
            float4 d0 = *(const float4*)(b1r + j);
            float4 d1 = *(const float4*)(b1r + j + 4);
            float va[8] = { a0.x + c0.x + d0.x, a0.y + c0.y + d0.y,
                            a0.z + c0.z + d0.z, a0.w + c0.w + d0.w,
                            a1.x + c1.x + d1.x, a1.y + c1.y + d1.y,
                            a1.z + c1.z + d1.z, a1.w + c1.w + d1.w };
            union { ushort u[8]; short8 v; } pk;
#pragma unroll
            for (int e = 0; e < 8; e++) {
                float x = va[e] > 0.f ? va[e] : 0.f;
                pk.u[e] = f2bf(x);
            }
            int byte = row * 1024 + (dc + j) * 2;
            byte ^= (row & 7) << 4;       // bank-conflict swizzle (G4)
            *reinterpret_cast<short8*>(reinterpret_cast<char*>(h1) + byte) = pk.v;
        }
    }
    __syncthreads();

    // ---- K-loop: wave w owns o in [w*64, w*64+64) ----
    int w = t >> 6, l = t & 63, lg = l >> 4, ll = l & 15;
    f32x4 acc[4][4] = {};
    for (int k = 0; k < DIM_; k += 32) {
        short8 a[4], b[4];
#pragma unroll
        for (int mt = 0; mt < 4; mt++) {
            int row = mt * 16 + ll;
            int byte = (row * 1024 + (k + 8 * lg) * 2) ^ ((row & 7) << 4);
            a[mt] = *reinterpret_cast<const short8*>(reinterpret_cast<const char*>(h1) + byte);
        }
#pragma unroll
        for (int ot = 0; ot < 4; ot++) {
            int o = w * 64 + ot * 16 + ll;
            b[ot] = *(const short8*)(W2b + o * DIM_ + k + 8 * lg);
        }
#pragma unroll
        for (int mt = 0; mt < 4; mt++)
#pragma unroll
            for (int ot = 0; ot < 4; ot++)
                acc[mt][ot] = __builtin_amdgcn_mfma_f32_16x16x32_bf16(a[mt], b[ot], acc[mt][ot], 0, 0, 0);
    }

    // ---- epilogue: relu(acc+b2)*W3, reduce over o ----
    __syncthreads();                       // h1 reads done; reuse as float accum
    float* logit = reinterpret_cast<float*>(h1);
    if (t < 64) logit[t] = 0.f;
    __syncthreads();
#pragma unroll
    for (int mt = 0; mt < 4; mt++) {
        float part[4] = {0.f, 0.f, 0.f, 0.f};
#pragma unroll
        for (int ot = 0; ot < 4; ot++) {
            int o = w * 64 + ot * 16 + ll;
            float bb = b2[o], w3 = W3[o];
#pragma unroll
            for (int reg = 0; reg < 4; reg++) {
                float v = acc[mt][ot][reg] + bb;
                v = v > 0.f ? v : 0.f;
                part[reg] += v * w3;
            }
        }
#pragma unroll
        for (int m = 1; m < 16; m <<= 1)
#pragma unroll
            for (int reg = 0; reg < 4; reg++) part[reg] += __shfl_xor(part[reg], m, 64);
        if (ll == 0) {
#pragma unroll
            for (int reg = 0; reg < 4; reg++)
                atomicAdd(&logit[mt * 16 + lg * 4 + reg], part[reg]);
        }
    }
    __syncthreads();
    if (t < 64) out[r0 + t] = logit[t] + b3[0];
}

extern "C" void kernel_launch(void* const* d_in, const int* in_sizes, int n_in,
                              void* d_out, int out_size, void* d_ws, size_t ws_size,
                              hipStream_t stream) {
    const float* P_f = (const float*)d_in[0];
    const float* emb = (const float*)d_in[1];
    const float* W_p = (const float*)d_in[2];
    const float* W_l = (const float*)d_in[3];
    const float* W1  = (const float*)d_in[4];
    const float* b1  = (const float*)d_in[5];
    const float* W2  = (const float*)d_in[6];
    const float* b2  = (const float*)d_in[7];
    const float* W3  = (const float*)d_in[8];
    const float* b3  = (const float*)d_in[9];
    const int*   L   = (const int*)d_in[10];   // harness passes integers as int32
    float* out = (float*)d_out;

    char* ws = (char*)d_ws;
    size_t off = 0;
    auto alloc = [&](size_t bytes) {
        void* p = ws + off;
        off = (off + bytes + 255) & ~(size_t)255;
        return p;
    };
    ushort* W2b  = (ushort*)alloc((size_t)OD_ * DIM_ * 2);
    ushort* MlT  = (ushort*)alloc((size_t)OD_ * LD_ * 2);
    float*  P_e  = (float*)alloc((size_t)S_ * DIM_ * 4);
    float*  hp   = (float*)alloc((size_t)S_ * DIM_ * 4);
    float*  hl   = (float*)alloc((size_t)NL_ * DIM_ * 4);

    k_cvt_w2<<<(OD_ * DIM_ / 4) / 256, 256, 0, stream>>>(W2, W2b);
    k_mlt<<<dim3(3, 64), 256, 0, stream>>>(W_l, W1, MlT);
    k_dot<<<S_, 512, 0, stream>>>(P_f, PD_, PD_, W_p, PD_, P_e);     // P_e = P_f @ W_p.T
    k_dot<<<S_, 512, 0, stream>>>(P_e, DIM_, DIM_, W1, 2 * DIM_, hp);// hp  = P_e @ W1p.T
    k_hl<<<(NL_ + 63) / 64, 512, 0, stream>>>(emb, L, MlT, hl);      // hl  = bf16(emb[L]) @ M_l
    k_main<<<(S_ * NL_) / 64, 512, 0, stream>>>(hp, hl, b1, W2b, b2, W3, b3, out);
}

// Round 3
// 369.703 us; speedup vs baseline: 1.9957x; 1.9957x over previous
//
#include <hip/hip_runtime.h>

typedef short short8 __attribute__((ext_vector_type(8)));
typedef float f32x4 __attribute__((ext_vector_type(4)));

#define S_   64
#define NL_  5000
#define PD_  1024
#define LD_  768
#define DIM_ 512
#define OD_  512

// main kernel tiling: BM=128 rows (2 s x 64 n), BN=256 (2 N-halves), BK=32
#define BK     32
#define KSTEPS 16          // DIM_/BK
#define NT_N   79          // ceil(5000/64)

__device__ __forceinline__ ushort f2bf(float f) {
    union { float f; unsigned u; } v; v.f = f;
    unsigned r = v.u + 0x7fffu + ((v.u >> 16) & 1u);   // RNE
    return (ushort)(r >> 16);
}
__device__ __forceinline__ float bf2f(ushort h) {
    union { unsigned u; float f; } v; v.u = ((unsigned)h) << 16;
    return v.f;
}
// XOR swizzle for 64B-stride row tiles: conflict-free for both our write
// pattern (8 consecutive lanes = 2 rows x 4 kslots) and read pattern
// (8 consecutive lanes = 8 consecutive rows, fixed kslot). Bijective.
__device__ __forceinline__ int swz(int row, int kslot) {
    return (row * 64 + kslot * 16) ^ (((row >> 1) & 7) << 4);
}
__device__ __forceinline__ void glds16(const void* g, void* l) {
    __builtin_amdgcn_global_load_lds(
        (const __attribute__((address_space(1))) void*)g,
        (__attribute__((address_space(3))) void*)l, 16, 0, 0);
}

// ---- W2 f32 -> bf16, scattered into pre-swizzled per-(nhalf,kt) panels ----
// Panel layout: nhalf*262144 + kt*16384 + swz(o&255, kslot); linear
// global_load_lds then reproduces the swizzled LDS image (rule #21).
__global__ void k_prep_w2(const float* __restrict__ W2, char* __restrict__ panel) {
    int c = blockIdx.x * 256 + threadIdx.x;        // 32768 16B-chunks
    int o = c >> 6, rem = c & 63, kt = rem >> 2, kslot = rem & 3;
    const float* src = W2 + o * DIM_ + kt * BK + kslot * 8;
    float4 v0 = *(const float4*)src;
    float4 v1 = *(const float4*)(src + 4);
    union { ushort u[8]; short8 v; } pk;
    pk.u[0] = f2bf(v0.x); pk.u[1] = f2bf(v0.y); pk.u[2] = f2bf(v0.z); pk.u[3] = f2bf(v0.w);
    pk.u[4] = f2bf(v1.x); pk.u[5] = f2bf(v1.y); pk.u[6] = f2bf(v1.z); pk.u[7] = f2bf(v1.w);
    char* dst = panel + (o >> 8) * (KSTEPS * 16384) + kt * 16384 + swz(o & 255, kslot);
    *(short8*)dst = pk.v;
}

// ---- M_lT[o][ld] = sum_dim W_l[dim][ld] * W1[o][512+dim]  (bf16 out) -------
__global__ void k_mlt(const float* __restrict__ W_l, const float* __restrict__ W1,
                      ushort* __restrict__ MlT) {
    __shared__ float w1r[8][DIM_];
    int o0 = blockIdx.y * 8;
    int ld = blockIdx.x * 256 + threadIdx.x;
    for (int i = threadIdx.x; i < 8 * DIM_; i += 256)
        w1r[i >> 9][i & 511] = W1[(o0 + (i >> 9)) * (2 * DIM_) + DIM_ + (i & 511)];
    __syncthreads();
    float acc[8] = {};
    for (int dim = 0; dim < DIM_; dim++) {
        float wl = W_l[dim * LD_ + ld];
#pragma unroll
        for (int oi = 0; oi < 8; oi++) acc[oi] += w1r[oi][dim] * wl;
    }
#pragma unroll
    for (int oi = 0; oi < 8; oi++) MlT[(o0 + oi) * LD_ + ld] = f2bf(acc[oi]);
}

// ---- small projection: C[s][o] = sum_k A[s][k]*W[o*ldw+k] (+bias) ----------
// 2 o-cols per block; threads = (s 0..63) x (kk 0..7); shfl-reduce over kk.
__global__ void k_proj(const float* __restrict__ A, int lda, int K,
                       const float* __restrict__ W, int ldw,
                       const float* __restrict__ bias, float* __restrict__ C) {
    int o0 = blockIdx.x * 2;
    int t = threadIdx.x, s = t >> 3, kk = t & 7;
    int kb = K >> 3, k0 = kk * kb;
    const float* a  = A + s * lda + k0;
    const float* w0 = W + (size_t)o0 * ldw + k0;
    const float* w1 = W + (size_t)(o0 + 1) * ldw + k0;
    float acc0 = 0.f, acc1 = 0.f;
    for (int k = 0; k < kb; k += 4) {
        float4 av  = *(const float4*)(a + k);
        float4 wv0 = *(const float4*)(w0 + k);
        float4 wv1 = *(const float4*)(w1 + k);
        acc0 += av.x * wv0.x + av.y * wv0.y + av.z * wv0.z + av.w * wv0.w;
        acc1 += av.x * wv1.x + av.y * wv1.y + av.z * wv1.z + av.w * wv1.w;
    }
#pragma unroll
    for (int m = 1; m < 8; m <<= 1) {
        acc0 += __shfl_xor(acc0, m, 64);
        acc1 += __shfl_xor(acc1, m, 64);
    }
    if (kk == 0) {
        C[s * DIM_ + o0]     = acc0 + (bias ? bias[o0] : 0.f);
        C[s * DIM_ + o0 + 1] = acc1 + (bias ? bias[o0 + 1] : 0.f);
    }
}

// ---- hl[5000][512] = bf16(emb[L]) @ MlT  (bf16 OUT now) --------------------
__global__ __launch_bounds__(512) void k_hl(const float* __restrict__ emb,
                                            const int* __restrict__ L,
                                            const ushort* __restrict__ MlT,
                                            ushort* __restrict__ hlB) {
    int t = threadIdx.x;
    int w = t >> 6, l = t & 63, lg = l >> 4, ll = l & 15;
    int r0 = blockIdx.x * 64;
    const float* arow[4];
#pragma unroll
    for (int mt = 0; mt < 4; mt++) {
        int r = r0 + mt * 16 + ll;
        if (r >= NL_) r = NL_ - 1;
        arow[mt] = emb + (long long)L[r] * LD_ + 8 * lg;
    }
    f32x4 acc[4][4] = {};
    for (int k = 0; k < LD_; k += 32) {
        short8 a[4], b[4];
#pragma unroll
        for (int mt = 0; mt < 4; mt++) {
            float4 v0 = *(const float4*)(arow[mt] + k);
            float4 v1 = *(const float4*)(arow[mt] + k + 4);
            union { ushort u[8]; short8 v; } pk;
            pk.u[0] = f2bf(v0.x); pk.u[1] = f2bf(v0.y);
            pk.u[2] = f2bf(v0.z); pk.u[3] = f2bf(v0.w);
            pk.u[4] = f2bf(v1.x); pk.u[5] = f2bf(v1.y);
            pk.u[6] = f2bf(v1.z); pk.u[7] = f2bf(v1.w);
            a[mt] = pk.v;
        }
#pragma unroll
        for (int ot = 0; ot < 4; ot++) {
            int o = w * 64 + ot * 16 + ll;
            b[ot] = *(const short8*)(MlT + o * LD_ + k + 8 * lg);
        }
#pragma unroll
        for (int mt = 0; mt < 4; mt++)
#pragma unroll
            for (int ot = 0; ot < 4; ot++)
                acc[mt][ot] = __builtin_amdgcn_mfma_f32_16x16x32_bf16(a[mt], b[ot], acc[mt][ot], 0, 0, 0);
    }
#pragma unroll
    for (int mt = 0; mt < 4; mt++)
#pragma unroll
        for (int ot = 0; ot < 4; ot++)
#pragma unroll
            for (int reg = 0; reg < 4; reg++) {
                int r = r0 + mt * 16 + lg * 4 + reg;
                if (r < NL_) hlB[(long long)r * DIM_ + w * 64 + ot * 16 + ll] = f2bf(acc[mt][ot][reg]);
            }
}

// ---- main: dbuf 2-phase GEMM, A computed on the fly ------------------------
// grid (79 n-tiles, 32 s-groups, 2 N-halves); 512 thr = 8 waves (2M x 4N).
// LDS 48KB: A[2]x8KB + B[2]x16KB -> 2 blocks/CU.
__global__ __launch_bounds__(512, 4) void k_main2(
    const ushort* __restrict__ hlB, const float* __restrict__ hpb,
    const char* __restrict__ panel, const float* __restrict__ b2,
    const float* __restrict__ W3, float* __restrict__ part) {
    __shared__ f32x4 ldsv[3072];            // 49152 B
    char* lds = (char*)ldsv;
    const int t = threadIdx.x;
    const int n0 = blockIdx.x * 64, s0 = blockIdx.y * 2, nh = blockIdx.z;
    const int w = t >> 6, lane = t & 63, lg = lane >> 4, ll = lane & 15;
    const int wr = w >> 2, wc = w & 3;      // 2M x 4N wave grid
    const char* pan = panel + nh * (KSTEPS * 16384);

    // A-staging ids: thread t stages one 16B chunk (row = t>>2, kslot = t&3)
    const int arow = t >> 2, akslot = t & 3;
    int an = n0 + (arow & 63); if (an >= NL_) an = NL_ - 1;
    const ushort* hlsrc = hlB + (size_t)an * DIM_ + akslot * 8;
    const float*  hpsrc = hpb + (s0 + (arow >> 6)) * DIM_ + akslot * 8;
    const int awz = swz(arow, akslot);

    // per-wave fragment read offsets (loop-invariant)
    int aoff[4], boff[4];
#pragma unroll
    for (int mt = 0; mt < 4; mt++) aoff[mt] = swz(wr * 64 + mt * 16 + ll, lg);
#pragma unroll
    for (int ot = 0; ot < 4; ot++) boff[ot] = swz(wc * 64 + ot * 16 + ll, lg);

    f32x4 acc[4][4] = {};

    auto stageB = [&](int kt, int buf) {
        const char* base = pan + kt * 16384;
        char* ldsB = lds + 16384 + buf * 16384;
#pragma unroll
        for (int r = 0; r < 2; r++) {
            int off = r * 8192 + w * 1024;
            glds16(base + off + (lane << 4), ldsB + off);
        }
    };
    auto packA = [&](int buf, short8 hv, float4 p0, float4 p1) {
        float hp8[8] = { p0.x, p0.y, p0.z, p0.w, p1.x, p1.y, p1.z, p1.w };
        union { ushort u[8]; short8 v; } pk;
#pragma unroll
        for (int e = 0; e < 8; e++) {
            float x = bf2f((ushort)hv[e]) + hp8[e];
            x = x > 0.f ? x : 0.f;
            pk.u[e] = f2bf(x);
        }
        *(short8*)(lds + buf * 8192 + awz) = pk.v;
    };

    // prologue: stage kt=0 into buf 0
    {
        short8 hv = *(const short8*)(hlsrc);
        float4 p0 = *(const float4*)(hpsrc);
        float4 p1 = *(const float4*)(hpsrc + 4);
        stageB(0, 0);
        packA(0, hv, p0, p1);
    }
    __syncthreads();

    for (int kt = 0; kt < KSTEPS; kt++) {
        const int cur = kt & 1, nxt = cur ^ 1;
        short8 hv; float4 p0, p1;
        if (kt < KSTEPS - 1) {
            stageB(kt + 1, nxt);                       // async, drains at barrier
            hv = *(const short8*)(hlsrc + (kt + 1) * BK);   // issue early (T14)
            p0 = *(const float4*)(hpsrc + (kt + 1) * BK);
            p1 = *(const float4*)(hpsrc + (kt + 1) * BK + 4);
        }
        const char* A = lds + cur * 8192;
        const char* B = lds + 16384 + cur * 16384;
        short8 a[4], b[4];
#pragma unroll
        for (int mt = 0; mt < 4; mt++) a[mt] = *(const short8*)(A + aoff[mt]);
#pragma unroll
        for (int ot = 0; ot < 4; ot++) b[ot] = *(const short8*)(B + boff[ot]);
#pragma unroll
        for (int mt = 0; mt < 4; mt++)
#pragma unroll
            for (int ot = 0; ot < 4; ot++)
                acc[mt][ot] = __builtin_amdgcn_mfma_f32_16x16x32_bf16(a[mt], b[ot], acc[mt][ot], 0, 0, 0);
        if (kt < KSTEPS - 1) packA(nxt, hv, p0, p1);   // consume late
        __syncthreads();
    }

    // ---- epilogue: relu(acc+b2)*W3, reduce over o; partial per N-half ----
    float* logit = (float*)lds;                        // reuse A buf 0
    if (t < 128) logit[t] = 0.f;
    __syncthreads();
#pragma unroll
    for (int mt = 0; mt < 4; mt++) {
        float p4[4] = { 0.f, 0.f, 0.f, 0.f };
#pragma unroll
        for (int ot = 0; ot < 4; ot++) {
            int o = nh * 256 + wc * 64 + ot * 16 + ll;
            float bb = b2[o], w3 = W3[o];
#pragma unroll
            for (int reg = 0; reg < 4; reg++) {
                float v = acc[mt][ot][reg] + bb;
                v = v > 0.f ? v : 0.f;
                p4[reg] += v * w3;
            }
        }
#pragma unroll
        for (int m = 1; m < 16; m <<= 1)
#pragma unroll
            for (int reg = 0; reg < 4; reg++) p4[reg] += __shfl_xor(p4[reg], m, 64);
        if (ll == 0)
#pragma unroll
            for (int reg = 0; reg < 4; reg++)
                atomicAdd(&logit[wr * 64 + mt * 16 + lg * 4 + reg], p4[reg]);
    }
    __syncthreads();
    if (t < 128) {
        int n = n0 + (t & 63);
        if (n < NL_)
            part[(size_t)nh * (S_ * NL_) + (size_t)(s0 + (t >> 6)) * NL_ + n] = logit[t];
    }
}

// ---- combine the two N-half partials ---------------------------------------
__global__ void k_combine(const float* __restrict__ part, const float* __restrict__ b3,
                          float* __restrict__ out) {
    int i = blockIdx.x * 256 + threadIdx.x;
    if (i < S_ * NL_) out[i] = part[i] + part[S_ * NL_ + i] + b3[0];
}

extern "C" void kernel_launch(void* const* d_in, const int* in_sizes, int n_in,
                              void* d_out, int out_size, void* d_ws, size_t ws_size,
                              hipStream_t stream) {
    const float* P_f = (const float*)d_in[0];
    const float* emb = (const float*)d_in[1];
    const float* W_p = (const float*)d_in[2];
    const float* W_l = (const float*)d_in[3];
    const float* W1  = (const float*)d_in[4];
    const float* b1  = (const float*)d_in[5];
    const float* W2  = (const float*)d_in[6];
    const float* b2  = (const float*)d_in[7];
    const float* W3  = (const float*)d_in[8];
    const float* b3  = (const float*)d_in[9];
    const int*   L   = (const int*)d_in[10];
    float* out = (float*)d_out;

    char* ws = (char*)d_ws;
    size_t off = 0;
    auto alloc = [&](size_t bytes) {
        void* p = ws + off;
        off = (off + bytes + 255) & ~(size_t)255;
        return p;
    };
    char*   panel = (char*)alloc((size_t)2 * KSTEPS * 16384);        // 512 KB
    ushort* MlT   = (ushort*)alloc((size_t)OD_ * LD_ * 2);           // 768 KB
    float*  P_e   = (float*)alloc((size_t)S_ * DIM_ * 4);
    float*  hpb   = (float*)alloc((size_t)S_ * DIM_ * 4);
    ushort* hlB   = (ushort*)alloc((size_t)NL_ * DIM_ * 2);          // 5.12 MB
    float*  part  = (float*)alloc((size_t)2 * S_ * NL_ * 4);         // 2.56 MB

    k_prep_w2<<<128, 256, 0, stream>>>(W2, panel);
    k_mlt<<<dim3(3, 64), 256, 0, stream>>>(W_l, W1, MlT);
    k_proj<<<256, 512, 0, stream>>>(P_f, PD_, PD_, W_p, PD_, nullptr, P_e);   // P_e
    k_proj<<<256, 512, 0, stream>>>(P_e, DIM_, DIM_, W1, 2 * DIM_, b1, hpb);  // hp+b1
    k_hl<<<NT_N, 512, 0, stream>>>(emb, L, MlT, hlB);
    k_main2<<<dim3(NT_N, 32, 2), 512, 0, stream>>>(hlB, hpb, panel, b2, W3, part);
    k_combine<<<1250, 256, 0, stream>>>(part, b3, out);
}

// Round 4
// 318.024 us; speedup vs baseline: 2.3200x; 1.1625x over previous
//
#include <hip/hip_runtime.h>
#include <hip/hip_bf16.h>

typedef short short8 __attribute__((ext_vector_type(8)));
typedef float f32x4 __attribute__((ext_vector_type(4)));

#define S_   64
#define NL_  5000
#define PD_  1024
#define LD_  768
#define DIM_ 512
#define OD_  512

#define BK     32
#define KSTEPS 16          // DIM_/BK
#define NT_M   79          // ceil(5000/64) row-tiles for main
#define HL_RT  157         // ceil(5000/32) row-tiles for hl

__device__ __forceinline__ ushort f2bf(float f) {
    union { float f; unsigned u; } v; v.f = f;
    unsigned r = v.u + 0x7fffu + ((v.u >> 16) & 1u);   // RNE
    return (ushort)(r >> 16);
}
__device__ __forceinline__ float bf2f(ushort h) {
    union { unsigned u; float f; } v; v.u = ((unsigned)h) << 16;
    return v.f;
}
// XOR swizzle for 64B-stride row tiles: conflict-free for write pattern
// (4 consecutive lanes = 1 row) and read pattern (16 lanes = 16 consecutive
// rows, fixed kslot). Bijective within each 1KB group.
__device__ __forceinline__ int swz(int row, int kslot) {
    return (row * 64 + kslot * 16) ^ (((row >> 1) & 7) << 4);
}
__device__ __forceinline__ void glds16(const void* g, void* l) {
    __builtin_amdgcn_global_load_lds(
        (const __attribute__((address_space(1))) void*)g,
        (__attribute__((address_space(3))) void*)l, 16, 0, 0);
}

// ==== pre-pass 1: {W2 panel prep | M_lT | P_e = P_f @ W_p.T} ================
// blocks 0..127: panel; 128..319: mlt; 320..831: proj1 (1 o-col each).
__global__ __launch_bounds__(256) void k_pre1(
    const float* __restrict__ W2, const float* __restrict__ W_l,
    const float* __restrict__ W1, const float* __restrict__ P_f,
    const float* __restrict__ W_p,
    char* __restrict__ panel, ushort* __restrict__ MlT, float* __restrict__ P_e) {
    __shared__ float w1r[8][DIM_];
    int b = blockIdx.x, t = threadIdx.x;
    if (b < 128) {
        // W2 f32 -> bf16 into pre-swizzled per-kt panel (rule #21: linear
        // global_load_lds later reproduces the swizzled LDS image).
        int c = b * 256 + t;                   // 32768 16B-chunks
        int o = c >> 6, rem = c & 63, kt = rem >> 2, kslot = rem & 3;
        const float* src = W2 + o * DIM_ + kt * BK + kslot * 8;
        float4 v0 = *(const float4*)src;
        float4 v1 = *(const float4*)(src + 4);
        union { ushort u[8]; short8 v; } pk;
        pk.u[0] = f2bf(v0.x); pk.u[1] = f2bf(v0.y); pk.u[2] = f2bf(v0.z); pk.u[3] = f2bf(v0.w);
        pk.u[4] = f2bf(v1.x); pk.u[5] = f2bf(v1.y); pk.u[6] = f2bf(v1.z); pk.u[7] = f2bf(v1.w);
        *(short8*)(panel + kt * 32768 + swz(o, kslot)) = pk.v;
    } else if (b < 320) {
        // M_lT[o][ld] = sum_dim W_l[dim][ld] * W1[o][512+dim]
        int bx = b - 128;
        int o0 = (bx / 3) * 8;
        int ld = (bx % 3) * 256 + t;
        for (int i = t; i < 8 * DIM_; i += 256)
            w1r[i >> 9][i & 511] = W1[(o0 + (i >> 9)) * (2 * DIM_) + DIM_ + (i & 511)];
        __syncthreads();
        float acc[8] = {};
        for (int dim = 0; dim < DIM_; dim++) {
            float wl = W_l[dim * LD_ + ld];
#pragma unroll
            for (int oi = 0; oi < 8; oi++) acc[oi] += w1r[oi][dim] * wl;
        }
#pragma unroll
        for (int oi = 0; oi < 8; oi++) MlT[(o0 + oi) * LD_ + ld] = f2bf(acc[oi]);
    } else {
        // P_e[s][o] = P_f[s] . W_p[o]; threads = 64 s x 4 kk
        int o = b - 320;
        int s = t >> 2, kk = t & 3;
        const float* a = P_f + s * PD_ + kk * 256;
        const float* w = W_p + (size_t)o * PD_ + kk * 256;
        float acc = 0.f;
        for (int k = 0; k < 256; k += 4) {
            float4 av = *(const float4*)(a + k);
            float4 wv = *(const float4*)(w + k);
            acc += av.x * wv.x + av.y * wv.y + av.z * wv.z + av.w * wv.w;
        }
        acc += __shfl_xor(acc, 1, 64);
        acc += __shfl_xor(acc, 2, 64);
        if (kk == 0) P_e[s * DIM_ + o] = acc;
    }
}

// ==== pre-pass 2: {hpb = P_e @ W1p.T + b1 | hlB = bf16(emb[L]) @ MlT} =======
// blocks 0..511: proj2; 512..825: hl (157 row-tiles x 2 o-halves).
__global__ __launch_bounds__(256) void k_pre2(
    const float* __restrict__ P_e, const float* __restrict__ W1,
    const float* __restrict__ b1, const float* __restrict__ emb,
    const int* __restrict__ L, const ushort* __restrict__ MlT,
    float* __restrict__ hpb, ushort* __restrict__ hlB) {
    int b = blockIdx.x, t = threadIdx.x;
    if (b < 512) {
        int o = b;
        int s = t >> 2, kk = t & 3;
        const float* a = P_e + s * DIM_ + kk * 128;
        const float* w = W1 + (size_t)o * (2 * DIM_) + kk * 128;
        float acc = 0.f;
        for (int k = 0; k < 128; k += 4) {
            float4 av = *(const float4*)(a + k);
            float4 wv = *(const float4*)(w + k);
            acc += av.x * wv.x + av.y * wv.y + av.z * wv.z + av.w * wv.w;
        }
        acc += __shfl_xor(acc, 1, 64);
        acc += __shfl_xor(acc, 2, 64);
        if (kk == 0) hpb[s * DIM_ + o] = acc + b1[o];
    } else {
        int hb = b - 512;                     // 0..313
        int rblk = hb % HL_RT, oh = hb / HL_RT;
        int r0 = rblk * 32;
        int w = t >> 6, l = t & 63, lg = l >> 4, ll = l & 15;
        const float* arow[2];
#pragma unroll
        for (int mt = 0; mt < 2; mt++) {
            int r = r0 + mt * 16 + ll;
            if (r >= NL_) r = NL_ - 1;
            arow[mt] = emb + (size_t)L[r] * LD_ + lg * 8;
        }
        f32x4 acc[2][4] = {};
        for (int k = 0; k < LD_; k += 32) {
            short8 a[2], bf[4];
#pragma unroll
            for (int mt = 0; mt < 2; mt++) {
                float4 v0 = *(const float4*)(arow[mt] + k);
                float4 v1 = *(const float4*)(arow[mt] + k + 4);
                union { ushort u[8]; short8 v; } pk;
                pk.u[0] = f2bf(v0.x); pk.u[1] = f2bf(v0.y);
                pk.u[2] = f2bf(v0.z); pk.u[3] = f2bf(v0.w);
                pk.u[4] = f2bf(v1.x); pk.u[5] = f2bf(v1.y);
                pk.u[6] = f2bf(v1.z); pk.u[7] = f2bf(v1.w);
                a[mt] = pk.v;
            }
#pragma unroll
            for (int ot = 0; ot < 4; ot++) {
                int o = oh * 256 + w * 64 + ot * 16 + ll;
                bf[ot] = *(const short8*)(MlT + o * LD_ + k + lg * 8);
            }
#pragma unroll
            for (int mt = 0; mt < 2; mt++)
#pragma unroll
                for (int ot = 0; ot < 4; ot++)
                    acc[mt][ot] = __builtin_amdgcn_mfma_f32_16x16x32_bf16(a[mt], bf[ot], acc[mt][ot], 0, 0, 0);
        }
#pragma unroll
        for (int mt = 0; mt < 2; mt++)
#pragma unroll
            for (int ot = 0; ot < 4; ot++)
#pragma unroll
                for (int reg = 0; reg < 4; reg++) {
                    int r = r0 + mt * 16 + lg * 4 + reg;
                    if (r < NL_)
                        hlB[(size_t)r * DIM_ + oh * 256 + w * 64 + ot * 16 + ll] = f2bf(acc[mt][ot][reg]);
                }
    }
}

// ==== main: BM=128 (2s x 64n) x BN=512 (full O), BK=32, dbuf 2-phase ========
// 8 waves (2M x 4N), wave tile 64x128, acc[4][8]. LDS 80KB -> 1 block/CU.
__global__ __launch_bounds__(512, 2) void k_main2(
    const ushort* __restrict__ hlB, const float* __restrict__ hpb,
    const char* __restrict__ panel, const float* __restrict__ b2,
    const float* __restrict__ W3, const float* __restrict__ b3,
    float* __restrict__ out) {
    __shared__ f32x4 ldsv[5120];            // 81920 B
    char* lds = (char*)ldsv;
    const int t = threadIdx.x;
    const int n0 = blockIdx.x * 64, s0 = blockIdx.y * 2;
    const int w = t >> 6, lane = t & 63, lg = lane >> 4, ll = lane & 15;
    const int wr = w >> 2, wc = w & 3;      // 2M x 4N wave grid

    // A-staging: thread t owns one 16B chunk (row = t>>2, kslot = t&3)
    const int arow = t >> 2, akslot = t & 3;
    int an = n0 + (arow & 63); if (an >= NL_) an = NL_ - 1;
    const ushort* hlsrc = hlB + (size_t)an * DIM_ + akslot * 8;
    const float*  hpsrc = hpb + (s0 + (arow >> 6)) * DIM_ + akslot * 8;
    const int awz = swz(arow, akslot);

    // per-wave fragment read offsets (loop-invariant)
    int aoff[4], boff[8];
#pragma unroll
    for (int mt = 0; mt < 4; mt++) aoff[mt] = swz(wr * 64 + mt * 16 + ll, lg);
#pragma unroll
    for (int ot = 0; ot < 8; ot++) boff[ot] = 16384 + swz(wc * 128 + ot * 16 + ll, lg);

    f32x4 acc[4][8] = {};

    auto stageB = [&](int kt, int buf) {
        const char* base = panel + kt * 32768;
        char* ldsB = lds + 16384 + buf * 32768;
#pragma unroll
        for (int r = 0; r < 4; r++) {
            int off = w * 4096 + r * 1024;
            glds16(base + off + (lane << 4), ldsB + off);
        }
    };
    auto packA = [&](int buf, short8 hv, float4 p0, float4 p1) {
        float hp8[8] = { p0.x, p0.y, p0.z, p0.w, p1.x, p1.y, p1.z, p1.w };
        float x[8];
#pragma unroll
        for (int e = 0; e < 8; e++) {
            float s = bf2f((ushort)hv[e]) + hp8[e];
            x[e] = s > 0.f ? s : 0.f;
        }
        union { __hip_bfloat162 h2[4]; short8 v; } pk;
#pragma unroll
        for (int e = 0; e < 4; e++)
            pk.h2[e] = __float22bfloat162_rn(make_float2(x[2 * e], x[2 * e + 1]));
        *(short8*)(lds + buf * 8192 + awz) = pk.v;
    };

    // prologue: stage kt=0 into buf 0
    {
        stageB(0, 0);
        short8 hv = *(const short8*)(hlsrc);
        float4 p0 = *(const float4*)(hpsrc);
        float4 p1 = *(const float4*)(hpsrc + 4);
        packA(0, hv, p0, p1);
    }
    __syncthreads();

    for (int kt = 0; kt < KSTEPS; kt++) {
        const int cur = kt & 1, nxt = cur ^ 1;
        short8 hv; float4 p0, p1;
        if (kt < KSTEPS - 1) {
            stageB(kt + 1, nxt);                          // async, drains at barrier
            hv = *(const short8*)(hlsrc + (kt + 1) * BK); // issue early (T14)
            p0 = *(const float4*)(hpsrc + (kt + 1) * BK);
            p1 = *(const float4*)(hpsrc + (kt + 1) * BK + 4);
        }
        const char* A = lds + cur * 8192;
        const char* B = lds + cur * 32768;
        short8 a[4], b[8];
#pragma unroll
        for (int mt = 0; mt < 4; mt++) a[mt] = *(const short8*)(A + aoff[mt]);
#pragma unroll
        for (int ot = 0; ot < 8; ot++) b[ot] = *(const short8*)(B + boff[ot]);
#pragma unroll
        for (int mt = 0; mt < 4; mt++)
#pragma unroll
            for (int ot = 0; ot < 8; ot++)
                acc[mt][ot] = __builtin_amdgcn_mfma_f32_16x16x32_bf16(a[mt], b[ot], acc[mt][ot], 0, 0, 0);
        if (kt < KSTEPS - 1) packA(nxt, hv, p0, p1);      // consume late
        __syncthreads();
    }

    // ---- epilogue: relu(acc+b2)*W3, reduce over o; direct out write ----
    float* logit = (float*)lds;                           // reuse A buf 0
    if (t < 128) logit[t] = 0.f;
    __syncthreads();
#pragma unroll
    for (int mt = 0; mt < 4; mt++) {
        float p4[4] = { 0.f, 0.f, 0.f, 0.f };
#pragma unroll
        for (int ot = 0; ot < 8; ot++) {
            int o = wc * 128 + ot * 16 + ll;
            float bb = b2[o], w3 = W3[o];
#pragma unroll
            for (int reg = 0; reg < 4; reg++) {
                float v = acc[mt][ot][reg] + bb;
                v = v > 0.f ? v : 0.f;
                p4[reg] += v * w3;
            }
        }
#pragma unroll
        for (int m = 1; m < 16; m <<= 1)
#pragma unroll
            for (int reg = 0; reg < 4; reg++) p4[reg] += __shfl_xor(p4[reg], m, 64);
        if (ll == 0)
#pragma unroll
            for (int reg = 0; reg < 4; reg++)
                atomicAdd(&logit[wr * 64 + mt * 16 + lg * 4 + reg], p4[reg]);
    }
    __syncthreads();
    if (t < 128) {
        int n = n0 + (t & 63);
        int s = s0 + (t >> 6);
        if (n < NL_) out[(size_t)s * NL_ + n] = logit[t] + b3[0];
    }
}

extern "C" void kernel_launch(void* const* d_in, const int* in_sizes, int n_in,
                              void* d_out, int out_size, void* d_ws, size_t ws_size,
                              hipStream_t stream) {
    const float* P_f = (const float*)d_in[0];
    const float* emb = (const float*)d_in[1];
    const float* W_p = (const float*)d_in[2];
    const float* W_l = (const float*)d_in[3];
    const float* W1  = (const float*)d_in[4];
    const float* b1  = (const float*)d_in[5];
    const float* W2  = (const float*)d_in[6];
    const float* b2  = (const float*)d_in[7];
    const float* W3  = (const float*)d_in[8];
    const float* b3  = (const float*)d_in[9];
    const int*   L   = (const int*)d_in[10];
    float* out = (float*)d_out;

    char* ws = (char*)d_ws;
    size_t off = 0;
    auto alloc = [&](size_t bytes) {
        void* p = ws + off;
        off = (off + bytes + 255) & ~(size_t)255;
        return p;
    };
    char*   panel = (char*)alloc((size_t)KSTEPS * 32768);            // 512 KB
    ushort* MlT   = (ushort*)alloc((size_t)OD_ * LD_ * 2);           // 768 KB
    float*  P_e   = (float*)alloc((size_t)S_ * DIM_ * 4);
    float*  hpb   = (float*)alloc((size_t)S_ * DIM_ * 4);
    ushort* hlB   = (ushort*)alloc((size_t)NL_ * DIM_ * 2);          // 5.12 MB

    k_pre1<<<832, 256, 0, stream>>>(W2, W_l, W1, P_f, W_p, panel, MlT, P_e);
    k_pre2<<<826, 256, 0, stream>>>(P_e, W1, b1, emb, L, MlT, hpb, hlB);
    k_main2<<<dim3(NT_M, 32), 512, 0, stream>>>(hlB, hpb, panel, b2, W3, b3, out);
}